// Round 2
// baseline (3173.628 us; speedup 1.0000x reference)
//
#include <hip/hip_runtime.h>
#include <math.h>

typedef __attribute__((ext_vector_type(8))) _Float16 half8;
typedef __attribute__((ext_vector_type(4))) float f32x4;

#define N_ 2048
#define T_ 64
#define D_ 512

// ---------------------------------------------------------------------------
// Workspace layout (bytes):
//   BtA   : half [1024][1024]  @ 0        (2 MB)  fused [Wzx|Wzh ; Wrx|Wrh], row=out col, contiguous k
//   BtB   : half [ 512][1024]  @ 2 MB     (1 MB)  fused [Whx|Whh]
//   h     : float[2048][512]   @ 3 MB     (4 MB)  fp32 master hidden state
//   h_hf  : half [2048][512]   @ 7 MB     (2 MB)  fp16 copy for GEMM A operand
//   zbuf  : float[2048][512]   @ 9 MB     (4 MB)
//   rh_hf : half [2048][512]   @ 13 MB    (2 MB)  r*h in fp16 for kernel B
// ---------------------------------------------------------------------------

__global__ __launch_bounds__(256) void prep_kernel(
    const float* __restrict__ Wzx, const float* __restrict__ Wzh,
    const float* __restrict__ Wrx, const float* __restrict__ Wrh,
    const float* __restrict__ Whx, const float* __restrict__ Whh,
    _Float16* __restrict__ BtA, _Float16* __restrict__ BtB,
    float* __restrict__ h, _Float16* __restrict__ h_hf)
{
  int i0 = blockIdx.x * 256 + threadIdx.x;
  int stride = gridDim.x * 256;
  // BtA[col][k], col in [0,1024), k in [0,1024)
  for (int idx = i0; idx < 1024 * 1024; idx += stride) {
    int col = idx >> 10, k = idx & 1023;
    const float* W = (col < 512) ? ((k < 512) ? Wzx : Wzh)
                                 : ((k < 512) ? Wrx : Wrh);
    BtA[idx] = (_Float16)W[(col & 511) * 512 + (k & 511)];
  }
  // BtB[col][k], col in [0,512), k in [0,1024)
  for (int idx = i0; idx < 512 * 1024; idx += stride) {
    int col = idx >> 10, k = idx & 1023;
    const float* W = (k < 512) ? Whx : Whh;
    BtB[idx] = (_Float16)W[col * 512 + (k & 511)];
  }
  // h0 = 0
  for (int idx = i0; idx < N_ * D_; idx += stride) {
    h[idx] = 0.f;
    h_hf[idx] = (_Float16)0.f;
  }
}

// ---------------------------------------------------------------------------
// One GEMM step.  MODE 0: gates pass  (NCOLS=1024, A=[x_t|h],  out: z, r*h)
//                 MODE 1: cand. pass  (NCOLS=512,  A=[x_t|rh], out: h_new)
// Tile 64x64, BK=64, 256 threads = 4 waves (2x2), each wave 32x32 = 2x2 frags
// of mfma_f32_16x16x32_f16.  C/D layout: col=lane&15, row=(lane>>4)*4+reg.
// A/B frag: lane holds 8 contiguous k at row/col = lane&15, k0 = (lane>>4)*8.
// ---------------------------------------------------------------------------
template <int MODE>
__global__ __launch_bounds__(256) void step_kernel(
    const float* __restrict__ X, const _Float16* __restrict__ Bt,
    const _Float16* __restrict__ Ahalf,   // h_hf (MODE 0) or rh_hf (MODE 1)
    const float* __restrict__ bz, const float* __restrict__ br,
    const float* __restrict__ bh,
    float* __restrict__ h, float* __restrict__ zbuf,
    _Float16* __restrict__ rh_hf, _Float16* __restrict__ h_hf,
    float* __restrict__ out, int t)
{
  __shared__ _Float16 As[64][72];   // +8 pad: conflict-free b128 reads (verified by hand: 8 dwords/bank)
  __shared__ _Float16 Bs[64][72];

  const int tid  = threadIdx.x;
  const int bm   = blockIdx.x;      // M tile (batch rows)
  const int bn   = blockIdx.y;      // N tile (output cols)
  const int lane = tid & 63;
  const int wid  = tid >> 6;
  const int wrow = wid >> 1;        // 0..1
  const int wcol = wid & 1;         // 0..1
  const int lr   = lane & 15;
  const int lk   = (lane >> 4) * 8;

  // staging: thread i -> row i/4, 16-elem group (i%4)*16
  const int sr = tid >> 2;
  const int sc = (tid & 3) * 16;

  f32x4 acc[2][2] = {};

  for (int kt = 0; kt < 16; ++kt) {
    const int kbase = kt * 64;
    // ---- stage A tile: [x_t | h-or-rh] rows bm*64.., k kbase.. ----
    {
      const int gm = bm * 64 + sr;
      const int kg = kbase + sc;
      half8 v0, v1;
      if (kg < 512) {  // x_t half (fp32 -> fp16)
        const float* src = X + ((size_t)gm * T_ + t) * D_ + kg;
        float4 f0 = ((const float4*)src)[0];
        float4 f1 = ((const float4*)src)[1];
        float4 f2 = ((const float4*)src)[2];
        float4 f3 = ((const float4*)src)[3];
        v0 = half8{(_Float16)f0.x, (_Float16)f0.y, (_Float16)f0.z, (_Float16)f0.w,
                   (_Float16)f1.x, (_Float16)f1.y, (_Float16)f1.z, (_Float16)f1.w};
        v1 = half8{(_Float16)f2.x, (_Float16)f2.y, (_Float16)f2.z, (_Float16)f2.w,
                   (_Float16)f3.x, (_Float16)f3.y, (_Float16)f3.z, (_Float16)f3.w};
      } else {         // recurrent half (already fp16)
        const _Float16* src = Ahalf + (size_t)gm * D_ + (kg - 512);
        v0 = *(const half8*)(src);
        v1 = *(const half8*)(src + 8);
      }
      *(half8*)(&As[sr][sc])     = v0;
      *(half8*)(&As[sr][sc + 8]) = v1;
    }
    // ---- stage B tile: Bt[col][k] ----
    {
      const int gc = bn * 64 + sr;
      const _Float16* src = Bt + (size_t)gc * 1024 + kbase + sc;
      *(half8*)(&Bs[sr][sc])     = *(const half8*)(src);
      *(half8*)(&Bs[sr][sc + 8]) = *(const half8*)(src + 8);
    }
    __syncthreads();

#pragma unroll
    for (int ks = 0; ks < 2; ++ks) {
      half8 a0 = *(const half8*)(&As[wrow * 32 + 0 + lr][ks * 32 + lk]);
      half8 a1 = *(const half8*)(&As[wrow * 32 + 16 + lr][ks * 32 + lk]);
      half8 b0 = *(const half8*)(&Bs[wcol * 32 + 0 + lr][ks * 32 + lk]);
      half8 b1 = *(const half8*)(&Bs[wcol * 32 + 16 + lr][ks * 32 + lk]);
      acc[0][0] = __builtin_amdgcn_mfma_f32_16x16x32_f16(a0, b0, acc[0][0], 0, 0, 0);
      acc[0][1] = __builtin_amdgcn_mfma_f32_16x16x32_f16(a0, b1, acc[0][1], 0, 0, 0);
      acc[1][0] = __builtin_amdgcn_mfma_f32_16x16x32_f16(a1, b0, acc[1][0], 0, 0, 0);
      acc[1][1] = __builtin_amdgcn_mfma_f32_16x16x32_f16(a1, b1, acc[1][1], 0, 0, 0);
    }
    __syncthreads();
  }

  // ---- epilogue ----
#pragma unroll
  for (int fr = 0; fr < 2; ++fr)
#pragma unroll
    for (int fc = 0; fc < 2; ++fc)
#pragma unroll
      for (int j = 0; j < 4; ++j) {
        const int m  = bm * 64 + wrow * 32 + fr * 16 + (lane >> 4) * 4 + j;
        const int cg = bn * 64 + wcol * 32 + fc * 16 + (lane & 15);
        const float v = acc[fr][fc][j];
        if (MODE == 0) {
          if (cg < 512) {
            const float zv = 1.f / (1.f + __expf(-(v + bz[cg])));
            zbuf[(size_t)m * D_ + cg] = zv;
          } else {
            const int d = cg - 512;
            const float rv = 1.f / (1.f + __expf(-(v + br[d])));
            rh_hf[(size_t)m * D_ + d] = (_Float16)(rv * h[(size_t)m * D_ + d]);
          }
        } else {
          const float ht = tanhf(v + bh[cg]);
          const float hp = h[(size_t)m * D_ + cg];
          const float zv = zbuf[(size_t)m * D_ + cg];
          const float hn = zv * hp + (1.f - zv) * ht;
          h[(size_t)m * D_ + cg]    = hn;
          h_hf[(size_t)m * D_ + cg] = (_Float16)hn;
          out[((size_t)m * T_ + t) * D_ + cg] = hn;
        }
      }
}

extern "C" void kernel_launch(void* const* d_in, const int* in_sizes, int n_in,
                              void* d_out, int out_size, void* d_ws, size_t ws_size,
                              hipStream_t stream) {
  (void)in_sizes; (void)n_in; (void)out_size; (void)ws_size;
  const float* X   = (const float*)d_in[0];
  const float* Wzx = (const float*)d_in[1];
  const float* Wzh = (const float*)d_in[2];
  const float* Wrx = (const float*)d_in[3];
  const float* Wrh = (const float*)d_in[4];
  const float* Whx = (const float*)d_in[5];
  const float* Whh = (const float*)d_in[6];
  const float* bz  = (const float*)d_in[7];
  const float* br  = (const float*)d_in[8];
  const float* bh  = (const float*)d_in[9];
  float* out = (float*)d_out;

  char* ws = (char*)d_ws;
  _Float16* BtA   = (_Float16*)(ws);
  _Float16* BtB   = (_Float16*)(ws + (size_t)(2 << 20));
  float*    h     = (float*)   (ws + (size_t)(3 << 20));
  _Float16* h_hf  = (_Float16*)(ws + (size_t)(7 << 20));
  float*    zbuf  = (float*)   (ws + (size_t)(9 << 20));
  _Float16* rh_hf = (_Float16*)(ws + (size_t)(13 << 20));

  prep_kernel<<<1024, 256, 0, stream>>>(Wzx, Wzh, Wrx, Wrh, Whx, Whh,
                                        BtA, BtB, h, h_hf);

  dim3 blk(256);
  dim3 gridA(N_ / 64, 1024 / 64);  // 32 x 16
  dim3 gridB(N_ / 64, 512 / 64);   // 32 x 8
  for (int t = 0; t < T_; ++t) {
    step_kernel<0><<<gridA, blk, 0, stream>>>(X, BtA, h_hf, bz, br, bh,
                                              h, zbuf, rh_hf, h_hf, out, t);
    step_kernel<1><<<gridB, blk, 0, stream>>>(X, BtB, rh_hf, bz, br, bh,
                                              h, zbuf, rh_hf, h_hf, out, t);
  }
}